// Round 1
// baseline (1399.272 us; speedup 1.0000x reference)
//
#include <hip/hip_runtime.h>
#include <math.h>

// ---------------------------------------------------------------------------
// Llama3-8B decode attention, fp32. B=128, H=4096, L=1024, 32 q heads,
// 8 kv heads (GQA rep=4), head_dim=128.
// Key simplification: k_new / wk are DEAD CODE in the reference (softmax over
// a length-1 axis is identically 1.0), so new_out == v_new. We never read wk.
// Pipeline: rmsnorm -> rope vector -> [q|v] GEMM (rope fused) -> attention
// (+v_new fused) -> output GEMM.
// ---------------------------------------------------------------------------

#define THREADS 256

__global__ __launch_bounds__(256) void rmsnorm_kernel(
    const float* __restrict__ x, const float* __restrict__ w,
    float* __restrict__ xn, int H) {
  int b = blockIdx.x;
  int t = threadIdx.x;
  const float4* x4 = (const float4*)(x + (size_t)b * H);
  const float4* w4 = (const float4*)w;
  float4* y4 = (float4*)(xn + (size_t)b * H);
  int n4 = H >> 2;
  float ss = 0.f;
  for (int i = t; i < n4; i += THREADS) {
    float4 v = x4[i];
    ss += v.x * v.x + v.y * v.y + v.z * v.z + v.w * v.w;
  }
#pragma unroll
  for (int off = 32; off; off >>= 1) ss += __shfl_xor(ss, off, 64);
  __shared__ float red[4];
  if ((t & 63) == 0) red[t >> 6] = ss;
  __syncthreads();
  float tot = red[0] + red[1] + red[2] + red[3];
  float rs = rsqrtf(tot / (float)H + 1e-5f);
  for (int i = t; i < n4; i += THREADS) {
    float4 v = x4[i];
    float4 g = w4[i];
    float4 o;
    o.x = v.x * rs * g.x;
    o.y = v.y * rs * g.y;
    o.z = v.z * rs * g.z;
    o.w = v.w * rs * g.w;
    y4[i] = o;
  }
}

// rope[d] = cos(a) - sin(a) for d<64, cos(a) + sin(a) for d>=64,
// a = L * theta^(-(d&63)/128). Double precision to match numpy float64.
__global__ void rope_kernel(float* __restrict__ rope, int L) {
  int d = threadIdx.x;  // 128 threads
  int i = d & 63;
  double ang = (double)L * pow(500000.0, -((double)i) / 128.0);
  double c = cos(ang), s = sin(ang);
  rope[d] = (float)(d < 64 ? c - s : c + s);
}

// Y[M x (n1+n2)] = X[M x K] @ [W1 | W2]; 32x32 tile per block, 256 threads,
// each thread: 1 row x 4 cols. Columns < n1 optionally scaled by
// rope[(globalcol)&127] (the q path); columns >= n1 go to Y2 (the v path).
__global__ __launch_bounds__(256) void gemm32(
    const float* __restrict__ X, int K,
    const float* __restrict__ W1, int n1,
    const float* __restrict__ W2, int n2,
    const float* __restrict__ rope,
    float* __restrict__ Y1, float* __restrict__ Y2) {
  __shared__ float xs[32][36];   // +pad: rows land on distinct bank groups
  __shared__ float wsh[32][36];
  int t = threadIdx.x;
  int colOff = blockIdx.x * 32;
  int rowOff = blockIdx.y * 32;
  bool reg2 = (colOff >= n1);
  const float* W = reg2 ? W2 : W1;
  int ld = reg2 ? n2 : n1;
  int c0 = reg2 ? colOff - n1 : colOff;
  int lr = t >> 3;   // 0..31: load row (X) / load k-row (W) / compute row
  int lc4 = t & 7;   // 0..7: f4 slot on load; col group on compute
  float4 acc = make_float4(0.f, 0.f, 0.f, 0.f);
  for (int kc = 0; kc < K; kc += 32) {
    float4 xv = *(const float4*)(X + (size_t)(rowOff + lr) * K + kc + lc4 * 4);
    float4 wv = *(const float4*)(W + (size_t)(kc + lr) * ld + c0 + lc4 * 4);
    xs[lr][lc4 * 4 + 0] = xv.x;
    xs[lr][lc4 * 4 + 1] = xv.y;
    xs[lr][lc4 * 4 + 2] = xv.z;
    xs[lr][lc4 * 4 + 3] = xv.w;
    *(float4*)(&wsh[lr][lc4 * 4]) = wv;
    __syncthreads();
#pragma unroll
    for (int k = 0; k < 32; k += 4) {
      float4 xq = *(const float4*)(&xs[lr][k]);
#pragma unroll
      for (int kk = 0; kk < 4; kk++) {
        float4 wq4 = *(const float4*)(&wsh[k + kk][lc4 * 4]);
        float xsc = (&xq.x)[kk];
        acc.x += xsc * wq4.x;
        acc.y += xsc * wq4.y;
        acc.z += xsc * wq4.z;
        acc.w += xsc * wq4.w;
      }
    }
    __syncthreads();
  }
  float4 o = acc;
  if (!reg2 && rope != nullptr) {
    float4 rp = *(const float4*)(rope + ((colOff + lc4 * 4) & 127));
    o.x *= rp.x;
    o.y *= rp.y;
    o.z *= rp.z;
    o.w *= rp.w;
  }
  float* Y = reg2 ? Y2 : Y1;
  *(float4*)(Y + (size_t)(rowOff + lr) * ld + c0 + lc4 * 4) = o;
}

// One block per (b, kv-head g). 4 waves = 4 rep query heads.
// Pass 1: stage 64-key tiles of K into LDS, each thread scores one (r, key).
// Softmax per wave (wave == r) over L=1024. Pass 2: stage V tiles, each
// thread accumulates 2 output dims for its r. Epilogue adds v_new.
__global__ __launch_bounds__(256) void attn_kernel(
    const float* __restrict__ q, const float* __restrict__ kc_,
    const float* __restrict__ vc_, const float* __restrict__ vnew,
    float* __restrict__ ho, int L) {
  __shared__ float sK[64][132];   // 33792 B; 132 = 128+4 pad (16B-aligned rows)
  __shared__ float sS[4][1024];   // 16384 B scores/probs
  __shared__ float sQ[4][128];    // 2048 B
  int t = threadIdx.x;
  int b = blockIdx.x >> 3;
  int g = blockIdx.x & 7;
  for (int i = t; i < 512; i += 256) {
    int r = i >> 7, d = i & 127;
    sQ[r][d] = q[(size_t)b * 4096 + (size_t)(g * 4 + r) * 128 + d];
  }
  __syncthreads();
  int r = t >> 6;      // wave id == rep head
  int l = t & 63;      // lane == key within tile
  const float scale = 0.08838834764831845f;  // 1/sqrt(128)
  int ntiles = L >> 6;
  const float* kbase = kc_ + (size_t)(b * 8 + g) * (size_t)L * 128;
  for (int tile = 0; tile < ntiles; tile++) {
    const float* src = kbase + (size_t)tile * 64 * 128;
#pragma unroll
    for (int i = 0; i < 8; i++) {
      int id = t + 256 * i;          // 2048 float4s = 64 rows x 32
      int lr = id >> 5, c4 = id & 31;
      float4 v = *(const float4*)(src + (size_t)lr * 128 + c4 * 4);
      *(float4*)(&sK[lr][c4 * 4]) = v;
    }
    __syncthreads();
    float4 a = make_float4(0.f, 0.f, 0.f, 0.f);
#pragma unroll
    for (int c4 = 0; c4 < 32; c4++) {
      float4 kv = *(const float4*)(&sK[l][c4 * 4]);
      float4 qv = *(const float4*)(&sQ[r][c4 * 4]);  // wave-uniform broadcast
      a.x += kv.x * qv.x;
      a.y += kv.y * qv.y;
      a.z += kv.z * qv.z;
      a.w += kv.w * qv.w;
    }
    sS[r][tile * 64 + l] = (a.x + a.y + a.z + a.w) * scale;
    __syncthreads();
  }
  // softmax over L, one wave per r (no cross-wave deps on sS)
  float m = -INFINITY;
  for (int i = 0; i < ntiles; i++) m = fmaxf(m, sS[r][l + 64 * i]);
#pragma unroll
  for (int off = 32; off; off >>= 1) m = fmaxf(m, __shfl_xor(m, off, 64));
  float sum = 0.f;
  for (int i = 0; i < ntiles; i++) {
    float e = __expf(sS[r][l + 64 * i] - m);
    sS[r][l + 64 * i] = e;
    sum += e;
  }
#pragma unroll
  for (int off = 32; off; off >>= 1) sum += __shfl_xor(sum, off, 64);
  float inv = 1.f / sum;
  for (int i = 0; i < ntiles; i++) sS[r][l + 64 * i] *= inv;
  __syncthreads();
  // pass 2: O = P @ V, 2 dims per thread
  int d0 = l * 2;
  float acc0 = 0.f, acc1 = 0.f;
  const float* vbase = vc_ + (size_t)(b * 8 + g) * (size_t)L * 128;
  for (int tile = 0; tile < ntiles; tile++) {
    const float* src = vbase + (size_t)tile * 64 * 128;
#pragma unroll
    for (int i = 0; i < 8; i++) {
      int id = t + 256 * i;
      int lr = id >> 5, c4 = id & 31;
      float4 v = *(const float4*)(src + (size_t)lr * 128 + c4 * 4);
      *(float4*)(&sK[lr][c4 * 4]) = v;
    }
    __syncthreads();
#pragma unroll
    for (int ll = 0; ll < 64; ll++) {
      float p = sS[r][tile * 64 + ll];               // wave-uniform broadcast
      float2 v = *(const float2*)(&sK[ll][d0]);
      acc0 += p * v.x;
      acc1 += p * v.y;
    }
    __syncthreads();
  }
  float2 vn = *(const float2*)(vnew + (size_t)b * 1024 + (size_t)g * 128 + d0);
  float2 o;
  o.x = acc0 + vn.x;
  o.y = acc1 + vn.y;
  *(float2*)(ho + (size_t)b * 4096 + (size_t)(g * 4 + r) * 128 + d0) = o;
}

extern "C" void kernel_launch(void* const* d_in, const int* in_sizes, int n_in,
                              void* d_out, int out_size, void* d_ws, size_t ws_size,
                              hipStream_t stream) {
  const float* x = (const float*)d_in[0];
  const float* kcache = (const float*)d_in[1];
  const float* vcache = (const float*)d_in[2];
  const float* normw = (const float*)d_in[3];
  const float* wq = (const float*)d_in[4];
  // d_in[5] (wk) intentionally unused: dead code in the reference.
  const float* wv = (const float*)d_in[6];
  const float* wo = (const float*)d_in[7];
  float* out = (float*)d_out;

  int H = in_sizes[3];                       // 4096
  int B = in_sizes[0] / H;                   // 128
  int Dq = in_sizes[4] / H;                  // 4096 = 32 heads * 128
  int Dv = in_sizes[6] / H;                  // 1024 = 8 kv heads * 128
  long long L = (long long)in_sizes[1] / ((long long)B * Dv);  // 1024

  // workspace layout (floats): xn | rope | q | vnew | ho  (~6.8 MB total)
  float* xn = (float*)d_ws;
  float* rope = xn + (size_t)B * H;
  float* qws = rope + 128;
  float* vnew = qws + (size_t)B * Dq;
  float* ho = vnew + (size_t)B * Dv;

  rmsnorm_kernel<<<B, 256, 0, stream>>>(x, normw, xn, H);
  rope_kernel<<<1, 128, 0, stream>>>(rope, (int)L);
  gemm32<<<dim3((Dq + Dv) / 32, B / 32), 256, 0, stream>>>(
      xn, H, wq, Dq, wv, Dv, rope, qws, vnew);
  attn_kernel<<<B * 8, 256, 0, stream>>>(qws, kcache, vcache, vnew, ho, (int)L);
  gemm32<<<dim3(H / 32, B / 32), 256, 0, stream>>>(
      ho, Dq, wo, H, nullptr, 0, nullptr, out, nullptr);
}